// Round 5
// baseline (1335.255 us; speedup 1.0000x reference)
//
#include <hip/hip_runtime.h>
#include <hip/hip_bf16.h>
#include <hip/hip_fp16.h>

// 2D DCT-II via folded (even/odd) f16 MFMA GEMMs:
//   y[k] = sum_{n<1024} (x[n] + (-1)^k x[2047-n]) * cos(pi*(2n+1)*k/4096)
// R5 change: GEMM LDS ring 4 buffers (128KB, 1 block/CU) -> 2 buffers
// (64KB, 2 blocks/CU = 4 waves/SIMD). Depth-1 prefetch with vmcnt(0) drain
// per tile; co-resident block hides the drain (m97/m114 mechanism).
// Cross-wave LDS WAR: explicit lgkmcnt(0) before ph2 barrier guarantees all
// reads of buf[t&1] complete before tile t+1's stage (issued after that
// barrier in ph1(t+1)... i.e. stage (t+1) issued in ph1(t) overwrites
// buf[(t+1)&1], last read in tile t-1, whose reads completed before the
// t-1 ph2 lgkmcnt+barrier). Swizzle (0 conflicts) + setprio retained.

typedef _Float16 half8 __attribute__((ext_vector_type(8)));
typedef float f32x4 __attribute__((ext_vector_type(4)));
typedef unsigned int uint32;

constexpr int BK = 32;
constexpr int BM = 256, BN = 256;
constexpr int KK = 1024;          // folded GEMM K
constexpr int NT = KK / BK;       // 32 K-tiles
constexpr int TILE_E = BM * BK;   // 8192 f16 = 16KB

__device__ __forceinline__ unsigned short f2h_bits(float f) {
  _Float16 h = (_Float16)f;
  return __builtin_bit_cast(unsigned short, h);
}
__device__ __forceinline__ float h2f(unsigned short u) {
  return (float)__builtin_bit_cast(_Float16, u);
}

__device__ __forceinline__ void gload_lds16(const unsigned short* g, unsigned short* l) {
  __builtin_amdgcn_global_load_lds((const __attribute__((address_space(1))) void*)g,
                                   (__attribute__((address_space(3))) void*)l,
                                   16, 0, 0);
}

#define CFENCE asm volatile("" ::: "memory")

// Stored f16 index for logical (tile row r, 16B k-slot byte cb); stored rows
// are 128B (two logical rows); slot' = ((r&1)<<2 | cb>>4) ^ ((r>>1)&7).
__device__ __forceinline__ int swz_idx(int r, int cbyte) {
  int b = (r >> 1) * 128 + ((((r & 1) << 6) | cbyte) ^ (((r >> 1) & 7) << 4));
  return b >> 1;
}

// Stage a 256x32 f16 tile from G (row-major, stride ld); LDS dest LINEAR,
// swizzle realized by inverse-permuting per-lane global source addresses.
__device__ __forceinline__ void stage_tile(const unsigned short* __restrict__ G,
                                           int rowbase, int k0, int ld,
                                           unsigned short* lds, int wave, int lane) {
#pragma unroll
  for (int c = 0; c < 2; ++c) {
    const int p = c * 64 + wave * 8 + (lane >> 3);   // stored 128B row
    const int v = (lane & 7) ^ ((lane >> 3) & 7);    // inverse slot swizzle
    const int r = 2 * p + (v >> 2);                  // logical tile row
    const int kslot = v & 3;
    const unsigned short* src = G + (size_t)(rowbase + r) * ld + (k0 + kslot * 8);
    unsigned short* dst = lds + (c * 64 + wave * 8) * 64;  // wave-uniform
    gload_lds16(src, dst);
  }
}

// ---- convert + stage-1 fold: Xf[m][n]=x[n]+x[2047-n], Xf[m][1024+n]=diff ---
__global__ __launch_bounds__(256) void cvt_fold1(const float* __restrict__ x,
                                                 unsigned short* __restrict__ Xf) {
  int tid = blockIdx.x * 256 + threadIdx.x;   // 2M threads
  int m = tid >> 7;                           // 16384 rows
  int n0 = (tid & 127) << 3;                  // 0..1016
  const float* row = x + (size_t)m * 2048;
  float4 a = *(const float4*)(row + n0);
  float4 b = *(const float4*)(row + n0 + 4);
  float4 c = *(const float4*)(row + 2040 - n0);
  float4 d = *(const float4*)(row + 2044 - n0);
  float f[8] = {a.x, a.y, a.z, a.w, b.x, b.y, b.z, b.w};
  float g[8] = {d.w, d.z, d.y, d.x, c.w, c.z, c.y, c.x};  // partner of n0+e
  uint32 up[4], um[4];
#pragma unroll
  for (int e = 0; e < 4; ++e) {
    up[e] = f2h_bits(f[2 * e] + g[2 * e]) |
            ((uint32)f2h_bits(f[2 * e + 1] + g[2 * e + 1]) << 16);
    um[e] = f2h_bits(f[2 * e] - g[2 * e]) |
            ((uint32)f2h_bits(f[2 * e + 1] - g[2 * e + 1]) << 16);
  }
  unsigned short* o = Xf + (size_t)m * 2048 + n0;
  *(uint4*)o = make_uint4(up[0], up[1], up[2], up[3]);
  *(uint4*)(o + 1024) = make_uint4(um[0], um[1], um[2], um[3]);
}

// ---- even/odd cosine matrices, 1024x1024 each -------------------------------
// Ce[k][n] = cos(pi*(2n+1)*(2k)/4096), Co[k][n] = cos(pi*(2n+1)*(2k+1)/4096)
__global__ __launch_bounds__(256) void gen_cos2(unsigned short* __restrict__ Ce,
                                                unsigned short* __restrict__ Co) {
  int idx = blockIdx.x * 256 + threadIdx.x;  // 1M
  int k = idx >> 10, n = idx & 1023;
  int tn = 2 * n + 1;
  int pe = (tn * (2 * k)) & 8191;
  int po = (tn * (2 * k + 1)) & 8191;
  const float s = 7.6699039394282061e-4f;  // pi/4096
  Ce[idx] = f2h_bits(cosf((float)pe * s));
  Co[idx] = f2h_bits(cosf((float)po * s));
}

// ---- stage-2 fold along m: U2[row][u]=Tt[u]+Tt[2047-u], [1024+u]=diff -------
__global__ __launch_bounds__(256) void fold2(const unsigned short* __restrict__ Tt,
                                             unsigned short* __restrict__ U2) {
  int tid = blockIdx.x * 256 + threadIdx.x;  // 2M threads
  int row = tid >> 7;                        // b*2048 + k, 16384 rows
  int j = (tid & 127) << 3;
  const unsigned short* p = Tt + (size_t)row * 2048;
  uint4 F = *(const uint4*)(p + j);
  uint4 Bv = *(const uint4*)(p + 2040 - j);
  uint32 fw[4] = {F.x, F.y, F.z, F.w};
  uint32 bw[4] = {Bv.x, Bv.y, Bv.z, Bv.w};
  float fe[8], ge[8];
#pragma unroll
  for (int e = 0; e < 8; ++e) {
    fe[e] = h2f((unsigned short)(fw[e >> 1] >> ((e & 1) * 16)));
    int pi = 7 - e;  // partner element within reversed 8-vector
    ge[e] = h2f((unsigned short)(bw[pi >> 1] >> ((pi & 1) * 16)));
  }
  uint32 up[4], um[4];
#pragma unroll
  for (int e = 0; e < 4; ++e) {
    up[e] = f2h_bits(fe[2 * e] + ge[2 * e]) |
            ((uint32)f2h_bits(fe[2 * e + 1] + ge[2 * e + 1]) << 16);
    um[e] = f2h_bits(fe[2 * e] - ge[2 * e]) |
            ((uint32)f2h_bits(fe[2 * e + 1] - ge[2 * e + 1]) << 16);
  }
  unsigned short* o = U2 + (size_t)row * 2048 + j;
  *(uint4*)o = make_uint4(up[0], up[1], up[2], up[3]);
  *(uint4*)(o + 1024) = make_uint4(um[0], um[1], um[2], um[3]);
}

// ---- pipelined GEMM, K=1024, 2-buffer ring, 2 blocks/CU ---------------------
// MODE 0: A = Xf (col half by bn), B = Ce/Co; OUT f16 transposed into
//         Tt[b][k_true][m]. MODE 1: A = Ce/Co, B = U2[z]; OUT fp32 row-major.
template <int MODE>
__global__ __launch_bounds__(512, 4) void dct_gemm(
    const unsigned short* __restrict__ Ce, const unsigned short* __restrict__ Co,
    const unsigned short* __restrict__ D, void* __restrict__ outp) {
  __shared__ unsigned short As[2 * TILE_E];
  __shared__ unsigned short Bs[2 * TILE_E];

  const int tid = threadIdx.x;
  const int lane = tid & 63;
  const int wave = tid >> 6;
  const int wr = wave >> 2;
  const int wc = wave & 3;
  const int bm = blockIdx.y * BM;
  const int bn = blockIdx.x * BN;
  const int z = blockIdx.z;

  const unsigned short* Ag;
  const unsigned short* Bg;
  int lda, ldb, arow, brow;
  bool half;
  if (MODE == 0) {
    half = (bn >= 1024);
    Ag = D + (half ? 1024 : 0); lda = 2048; arow = bm;
    Bg = half ? Co : Ce;        ldb = 1024; brow = bn - (half ? 1024 : 0);
  } else {
    half = (bm >= 1024);
    Ag = half ? Co : Ce;        lda = 1024; arow = bm - (half ? 1024 : 0);
    Bg = D + (size_t)z * 4194304u + (half ? 1024 : 0);
    ldb = 2048; brow = bn;
  }

  const int frc = lane & 15;
  const int cb = (lane >> 4) << 4;

  f32x4 acc[8][4] = {};

  stage_tile(Ag, arow, 0, lda, &As[0], wave, lane);
  stage_tile(Bg, brow, 0, ldb, &Bs[0], wave, lane);
  asm volatile("s_waitcnt vmcnt(0)" ::: "memory");
  CFENCE; __builtin_amdgcn_s_barrier(); CFENCE;

  for (int t = 0; t < NT; ++t) {
    const unsigned short* at = &As[(t & 1) * TILE_E];
    const unsigned short* bt = &Bs[(t & 1) * TILE_E];
    half8 af[4], bf[4];

    // phase 1: reads (quadrant mh=0) + stage both next-tile operands
#pragma unroll
    for (int m = 0; m < 4; ++m)
      af[m] = *(const half8*)&at[swz_idx(wr * 128 + m * 16 + frc, cb)];
#pragma unroll
    for (int n = 0; n < 4; ++n)
      bf[n] = *(const half8*)&bt[swz_idx(wc * 64 + n * 16 + frc, cb)];
    if (t + 1 < NT) {
      stage_tile(Ag, arow, (t + 1) * BK, lda, &As[((t + 1) & 1) * TILE_E], wave, lane);
      stage_tile(Bg, brow, (t + 1) * BK, ldb, &Bs[((t + 1) & 1) * TILE_E], wave, lane);
    }
    CFENCE; __builtin_amdgcn_s_barrier(); CFENCE;
    __builtin_amdgcn_s_setprio(1);
#pragma unroll
    for (int m = 0; m < 4; ++m)
#pragma unroll
      for (int n = 0; n < 4; ++n)
        acc[m][n] = __builtin_amdgcn_mfma_f32_16x16x32_f16(af[m], bf[n], acc[m][n], 0, 0, 0);
    __builtin_amdgcn_s_setprio(0);

    // phase 2: reads (quadrant mh=1); release this buffer (lgkm) and next
    // tile's loads (vmcnt) before the barrier.
#pragma unroll
    for (int m = 0; m < 4; ++m)
      af[m] = *(const half8*)&at[swz_idx(wr * 128 + 64 + m * 16 + frc, cb)];
    asm volatile("s_waitcnt lgkmcnt(0)" ::: "memory");
    __builtin_amdgcn_sched_barrier(0);
    if (t + 1 < NT)
      asm volatile("s_waitcnt vmcnt(0)" ::: "memory");
    CFENCE; __builtin_amdgcn_s_barrier(); CFENCE;
    __builtin_amdgcn_s_setprio(1);
#pragma unroll
    for (int m = 0; m < 4; ++m)
#pragma unroll
      for (int n = 0; n < 4; ++n)
        acc[m + 4][n] =
            __builtin_amdgcn_mfma_f32_16x16x32_f16(af[m], bf[n], acc[m + 4][n], 0, 0, 0);
    __builtin_amdgcn_s_setprio(0);
  }

  // epilogue; D mapping: col = lane&15, row = (lane>>4)*4 + i
  const int koff = half ? 1024 : 0;
  if (MODE == 0) {
    unsigned short* Tt = (unsigned short*)outp;
#pragma unroll
    for (int mi = 0; mi < 8; ++mi) {
      const int r = bm + wr * 128 + (mi >> 2) * 64 + (mi & 3) * 16 + (lane >> 4) * 4;
      const int b = r >> 11;
      const int rb = r & 2047;
#pragma unroll
      for (int n = 0; n < 4; ++n) {
        const int cpk = bn + wc * 64 + n * 16 + frc;
        const int ktrue = 2 * (cpk - koff) + (half ? 1 : 0);
        uint32 lo = f2h_bits(acc[mi][n][0]) | ((uint32)f2h_bits(acc[mi][n][1]) << 16);
        uint32 hi = f2h_bits(acc[mi][n][2]) | ((uint32)f2h_bits(acc[mi][n][3]) << 16);
        *(uint2*)&Tt[(size_t)b * 4194304 + (size_t)ktrue * 2048 + rb] =
            make_uint2(lo, hi);
      }
    }
  } else {
    float* out = (float*)outp + (size_t)z * 4194304;
#pragma unroll
    for (int mi = 0; mi < 8; ++mi) {
      const int p0 =
          bm + wr * 128 + (mi >> 2) * 64 + (mi & 3) * 16 + (lane >> 4) * 4 - koff;
#pragma unroll
      for (int n = 0; n < 4; ++n) {
        const int cg = bn + wc * 64 + n * 16 + frc;
#pragma unroll
        for (int i = 0; i < 4; ++i) {
          const int rtrue = 2 * (p0 + i) + (half ? 1 : 0);
          out[(size_t)rtrue * 2048 + cg] = acc[mi][n][i];
        }
      }
    }
  }
}

extern "C" void kernel_launch(void* const* d_in, const int* in_sizes, int n_in,
                              void* d_out, int out_size, void* d_ws,
                              size_t ws_size, hipStream_t stream) {
  const float* x = (const float*)d_in[0];
  float* out = (float*)d_out;

  // workspace (f16 elems): Xf/U2 33554432 | Ce 1048576 | Co 1048576 | Tt 33554432
  unsigned short* Xf = (unsigned short*)d_ws;  // aliased as U2 after GEMM1
  unsigned short* Ce = Xf + 33554432u;
  unsigned short* Co = Ce + 1048576u;
  unsigned short* Tt = Co + 1048576u;

  cvt_fold1<<<8192, 256, 0, stream>>>(x, Xf);
  gen_cos2<<<4096, 256, 0, stream>>>(Ce, Co);
  // stage 1: T[m][k] over folded K=1024; writes Tt[b][k_true][m] (f16)
  dct_gemm<0><<<dim3(8, 64, 1), 512, 0, stream>>>(Ce, Co, Xf, (void*)Tt);
  // stage 2 fold along m (Xf region reused as U2)
  fold2<<<8192, 256, 0, stream>>>(Tt, Xf);
  // stage 2: out[b] rows parity-unpacked, fp32
  dct_gemm<1><<<dim3(8, 8, 8), 512, 0, stream>>>(Ce, Co, Xf, (void*)out);
}

// Round 6
// 237.631 us; speedup vs baseline: 5.6190x; 5.6190x over previous
//
#include <hip/hip_runtime.h>
#include <hip/hip_bf16.h>
#include <hip/hip_fp16.h>

// 2D DCT-II via folded (even/odd) f16 MFMA GEMMs:
//   y[k] = sum_{n<1024} (x[n] + (-1)^k x[2047-n]) * cos(pi*(2n+1)*k/4096)
// GEMM: 256x256 tile, 8 waves (2Mx4N), m201-style 8-phase schedule:
//   iter = 2 K-tiles (BK=32); phase = one C-quadrant (8 MFMA) + <=6 ds_read
//   + exactly 1 staging global_load_lds; counted vmcnt(4) at phases 4,8 only.
// LDS = 2 iter-buffers x (A 32KB + B 32KB) = 128 KB, 1 block/CU.
// Ledger (verified): after every vmcnt(4), outstanding = most recent 4 issues;
// kt0 resident via prev iter ph8 wait, kt1 via this iter ph4 wait; stage
// target buffer b^1 is only read next iter (WAR separated by barriers).
// NOTE: no min-waves launch_bounds — R5 showed (512,4) forces acc spill.

typedef _Float16 half8 __attribute__((ext_vector_type(8)));
typedef float f32x4 __attribute__((ext_vector_type(4)));
typedef unsigned int uint32;

constexpr int KK = 1024;          // folded GEMM K
constexpr int NITER = KK / 64;    // 16 iterations x 2 K-tiles(32)
constexpr int SUB_E = 8192;       // 256x32 f16 subtile = 16 KB

__device__ __forceinline__ unsigned short f2h_bits(float f) {
  _Float16 h = (_Float16)f;
  return __builtin_bit_cast(unsigned short, h);
}
__device__ __forceinline__ float h2f(unsigned short u) {
  return (float)__builtin_bit_cast(_Float16, u);
}

__device__ __forceinline__ void gload_lds16(const unsigned short* g, unsigned short* l) {
  __builtin_amdgcn_global_load_lds((const __attribute__((address_space(1))) void*)g,
                                   (__attribute__((address_space(3))) void*)l,
                                   16, 0, 0);
}

#define CFENCE asm volatile("" ::: "memory")
#define BARRIER do { CFENCE; __builtin_amdgcn_s_barrier(); CFENCE; } while (0)

// Stored f16 index for logical (tile row r, 16B k-slot byte cb); stored rows
// are 128B (two logical rows); slot' = ((r&1)<<2 | cb>>4) ^ ((r>>1)&7).
// Measured 0 bank conflicts (R2-R4).
__device__ __forceinline__ int swz_idx(int r, int cbyte) {
  int b = (r >> 1) * 128 + ((((r & 1) << 6) | cbyte) ^ (((r >> 1) & 7) << 4));
  return b >> 1;
}

// One half (c=0,1) of staging a 256x32 f16 subtile: 1 global_load_lds/thread.
// LDS dest LINEAR; swizzle realized by inverse-permuting global source.
__device__ __forceinline__ void stage_half(const unsigned short* __restrict__ G,
                                           int rowbase, int k0, int ld,
                                           unsigned short* lds, int wave, int lane,
                                           int c) {
  const int p = c * 64 + wave * 8 + (lane >> 3);   // stored 128B row
  const int v = (lane & 7) ^ ((lane >> 3) & 7);    // inverse slot swizzle
  const int r = 2 * p + (v >> 2);                  // logical tile row
  const int kslot = v & 3;
  gload_lds16(G + (size_t)(rowbase + r) * ld + (k0 + kslot * 8),
              lds + (c * 64 + wave * 8) * 64);
}

// ---- convert + stage-1 fold: Xf[m][n]=x[n]+x[2047-n], Xf[m][1024+n]=diff ---
__global__ __launch_bounds__(256) void cvt_fold1(const float* __restrict__ x,
                                                 unsigned short* __restrict__ Xf) {
  int tid = blockIdx.x * 256 + threadIdx.x;
  int m = tid >> 7;
  int n0 = (tid & 127) << 3;
  const float* row = x + (size_t)m * 2048;
  float4 a = *(const float4*)(row + n0);
  float4 b = *(const float4*)(row + n0 + 4);
  float4 c = *(const float4*)(row + 2040 - n0);
  float4 d = *(const float4*)(row + 2044 - n0);
  float f[8] = {a.x, a.y, a.z, a.w, b.x, b.y, b.z, b.w};
  float g[8] = {d.w, d.z, d.y, d.x, c.w, c.z, c.y, c.x};
  uint32 up[4], um[4];
#pragma unroll
  for (int e = 0; e < 4; ++e) {
    up[e] = f2h_bits(f[2 * e] + g[2 * e]) |
            ((uint32)f2h_bits(f[2 * e + 1] + g[2 * e + 1]) << 16);
    um[e] = f2h_bits(f[2 * e] - g[2 * e]) |
            ((uint32)f2h_bits(f[2 * e + 1] - g[2 * e + 1]) << 16);
  }
  unsigned short* o = Xf + (size_t)m * 2048 + n0;
  *(uint4*)o = make_uint4(up[0], up[1], up[2], up[3]);
  *(uint4*)(o + 1024) = make_uint4(um[0], um[1], um[2], um[3]);
}

// ---- even/odd cosine matrices, 1024x1024 each -------------------------------
__global__ __launch_bounds__(256) void gen_cos2(unsigned short* __restrict__ Ce,
                                                unsigned short* __restrict__ Co) {
  int idx = blockIdx.x * 256 + threadIdx.x;
  int k = idx >> 10, n = idx & 1023;
  int tn = 2 * n + 1;
  int pe = (tn * (2 * k)) & 8191;
  int po = (tn * (2 * k + 1)) & 8191;
  const float s = 7.6699039394282061e-4f;  // pi/4096
  Ce[idx] = f2h_bits(cosf((float)pe * s));
  Co[idx] = f2h_bits(cosf((float)po * s));
}

// ---- stage-2 fold along m ---------------------------------------------------
__global__ __launch_bounds__(256) void fold2(const unsigned short* __restrict__ Tt,
                                             unsigned short* __restrict__ U2) {
  int tid = blockIdx.x * 256 + threadIdx.x;
  int row = tid >> 7;
  int j = (tid & 127) << 3;
  const unsigned short* p = Tt + (size_t)row * 2048;
  uint4 F = *(const uint4*)(p + j);
  uint4 Bv = *(const uint4*)(p + 2040 - j);
  uint32 fw[4] = {F.x, F.y, F.z, F.w};
  uint32 bw[4] = {Bv.x, Bv.y, Bv.z, Bv.w};
  float fe[8], ge[8];
#pragma unroll
  for (int e = 0; e < 8; ++e) {
    fe[e] = h2f((unsigned short)(fw[e >> 1] >> ((e & 1) * 16)));
    int pi = 7 - e;
    ge[e] = h2f((unsigned short)(bw[pi >> 1] >> ((pi & 1) * 16)));
  }
  uint32 up[4], um[4];
#pragma unroll
  for (int e = 0; e < 4; ++e) {
    up[e] = f2h_bits(fe[2 * e] + ge[2 * e]) |
            ((uint32)f2h_bits(fe[2 * e + 1] + ge[2 * e + 1]) << 16);
    um[e] = f2h_bits(fe[2 * e] - ge[2 * e]) |
            ((uint32)f2h_bits(fe[2 * e + 1] - ge[2 * e + 1]) << 16);
  }
  unsigned short* o = U2 + (size_t)row * 2048 + j;
  *(uint4*)o = make_uint4(up[0], up[1], up[2], up[3]);
  *(uint4*)(o + 1024) = make_uint4(um[0], um[1], um[2], um[3]);
}

// ---- 8-phase pipelined GEMM, K=1024 ----------------------------------------
template <int MODE>
__global__ __launch_bounds__(512) void dct_gemm(
    const unsigned short* __restrict__ Ce, const unsigned short* __restrict__ Co,
    const unsigned short* __restrict__ D, void* __restrict__ outp) {
  __shared__ unsigned short As[4 * SUB_E];  // [buf][kt][8192]
  __shared__ unsigned short Bs[4 * SUB_E];

  const int tid = threadIdx.x;
  const int lane = tid & 63;
  const int wave = tid >> 6;
  const int wr = wave >> 2;
  const int wc = wave & 3;
  const int bm = blockIdx.y * 256;
  const int bn = blockIdx.x * 256;
  const int z = blockIdx.z;

  const unsigned short* Ag;
  const unsigned short* Bg;
  int lda, ldb, arow, brow;
  bool half;
  if (MODE == 0) {
    half = (bn >= 1024);
    Ag = D + (half ? 1024 : 0); lda = 2048; arow = bm;
    Bg = half ? Co : Ce;        ldb = 1024; brow = bn - (half ? 1024 : 0);
  } else {
    half = (bm >= 1024);
    Ag = half ? Co : Ce;        lda = 1024; arow = bm - (half ? 1024 : 0);
    Bg = D + (size_t)z * 4194304u + (half ? 1024 : 0);
    ldb = 2048; brow = bn;
  }

  const int frc = lane & 15;
  const int cb = (lane >> 4) << 4;

  f32x4 acc[8][4] = {};

  // prologue: stage iter-0's kt0, kt1 into buf0 (8 loads); wait kt0 (oldest 4)
  stage_half(Ag, arow, 0, lda, &As[0 * SUB_E], wave, lane, 0);
  stage_half(Ag, arow, 0, lda, &As[0 * SUB_E], wave, lane, 1);
  stage_half(Bg, brow, 0, ldb, &Bs[0 * SUB_E], wave, lane, 0);
  stage_half(Bg, brow, 0, ldb, &Bs[0 * SUB_E], wave, lane, 1);
  stage_half(Ag, arow, 32, lda, &As[1 * SUB_E], wave, lane, 0);
  stage_half(Ag, arow, 32, lda, &As[1 * SUB_E], wave, lane, 1);
  stage_half(Bg, brow, 32, ldb, &Bs[1 * SUB_E], wave, lane, 0);
  stage_half(Bg, brow, 32, ldb, &Bs[1 * SUB_E], wave, lane, 1);
  asm volatile("s_waitcnt vmcnt(4)" ::: "memory");
  BARRIER;

  for (int i = 0; i < NITER; ++i) {
    const int b = i & 1;
    const unsigned short* a0 = &As[(b * 2 + 0) * SUB_E];
    const unsigned short* a1 = &As[(b * 2 + 1) * SUB_E];
    const unsigned short* bt0 = &Bs[(b * 2 + 0) * SUB_E];
    const unsigned short* bt1 = &Bs[(b * 2 + 1) * SUB_E];
    unsigned short* nA0 = &As[((b ^ 1) * 2 + 0) * SUB_E];
    unsigned short* nA1 = &As[((b ^ 1) * 2 + 1) * SUB_E];
    unsigned short* nB0 = &Bs[((b ^ 1) * 2 + 0) * SUB_E];
    unsigned short* nB1 = &Bs[((b ^ 1) * 2 + 1) * SUB_E];
    const int kn = (i + 1) * 64;
    const bool st = (i + 1 < NITER);

    half8 af[4], bf0[2], bf1[2];

    // ========== K-tile 0 ==========
    // ph1: Q(0,0) reads + stage A(kt0) half0
#pragma unroll
    for (int m = 0; m < 4; ++m)
      af[m] = *(const half8*)&a0[swz_idx(wr * 128 + m * 16 + frc, cb)];
#pragma unroll
    for (int n = 0; n < 2; ++n)
      bf0[n] = *(const half8*)&bt0[swz_idx(wc * 64 + n * 16 + frc, cb)];
    if (st) stage_half(Ag, arow, kn, lda, nA0, wave, lane, 0);
    BARRIER;
    __builtin_amdgcn_s_setprio(1);
#pragma unroll
    for (int m = 0; m < 4; ++m)
#pragma unroll
      for (int n = 0; n < 2; ++n)
        acc[m][n] = __builtin_amdgcn_mfma_f32_16x16x32_f16(af[m], bf0[n], acc[m][n], 0, 0, 0);
    __builtin_amdgcn_s_setprio(0);
    BARRIER;
    // ph2: Q(0,1) reads + stage A(kt0) half1
#pragma unroll
    for (int n = 0; n < 2; ++n)
      bf1[n] = *(const half8*)&bt0[swz_idx(wc * 64 + (n + 2) * 16 + frc, cb)];
    if (st) stage_half(Ag, arow, kn, lda, nA0, wave, lane, 1);
    BARRIER;
    __builtin_amdgcn_s_setprio(1);
#pragma unroll
    for (int m = 0; m < 4; ++m)
#pragma unroll
      for (int n = 0; n < 2; ++n)
        acc[m][n + 2] = __builtin_amdgcn_mfma_f32_16x16x32_f16(af[m], bf1[n], acc[m][n + 2], 0, 0, 0);
    __builtin_amdgcn_s_setprio(0);
    BARRIER;
    // ph3: Q(1,0) reads + stage B(kt0) half0
#pragma unroll
    for (int m = 0; m < 4; ++m)
      af[m] = *(const half8*)&a0[swz_idx(wr * 128 + 64 + m * 16 + frc, cb)];
    if (st) stage_half(Bg, brow, kn, ldb, nB0, wave, lane, 0);
    BARRIER;
    __builtin_amdgcn_s_setprio(1);
#pragma unroll
    for (int m = 0; m < 4; ++m)
#pragma unroll
      for (int n = 0; n < 2; ++n)
        acc[m + 4][n] = __builtin_amdgcn_mfma_f32_16x16x32_f16(af[m], bf0[n], acc[m + 4][n], 0, 0, 0);
    __builtin_amdgcn_s_setprio(0);
    BARRIER;
    // ph4: Q(1,1) + stage B(kt0) half1 + counted wait (kt1 resident after)
    if (st) stage_half(Bg, brow, kn, ldb, nB0, wave, lane, 1);
    if (st)
      asm volatile("s_waitcnt vmcnt(4)" ::: "memory");
    else
      asm volatile("s_waitcnt vmcnt(0)" ::: "memory");
    BARRIER;
    __builtin_amdgcn_s_setprio(1);
#pragma unroll
    for (int m = 0; m < 4; ++m)
#pragma unroll
      for (int n = 0; n < 2; ++n)
        acc[m + 4][n + 2] = __builtin_amdgcn_mfma_f32_16x16x32_f16(af[m], bf1[n], acc[m + 4][n + 2], 0, 0, 0);
    __builtin_amdgcn_s_setprio(0);
    BARRIER;

    // ========== K-tile 1 ==========
    // ph5: Q(0,0) reads + stage A(kt1) half0
#pragma unroll
    for (int m = 0; m < 4; ++m)
      af[m] = *(const half8*)&a1[swz_idx(wr * 128 + m * 16 + frc, cb)];
#pragma unroll
    for (int n = 0; n < 2; ++n)
      bf0[n] = *(const half8*)&bt1[swz_idx(wc * 64 + n * 16 + frc, cb)];
    if (st) stage_half(Ag, arow, kn + 32, lda, nA1, wave, lane, 0);
    BARRIER;
    __builtin_amdgcn_s_setprio(1);
#pragma unroll
    for (int m = 0; m < 4; ++m)
#pragma unroll
      for (int n = 0; n < 2; ++n)
        acc[m][n] = __builtin_amdgcn_mfma_f32_16x16x32_f16(af[m], bf0[n], acc[m][n], 0, 0, 0);
    __builtin_amdgcn_s_setprio(0);
    BARRIER;
    // ph6: Q(0,1) + stage A(kt1) half1
#pragma unroll
    for (int n = 0; n < 2; ++n)
      bf1[n] = *(const half8*)&bt1[swz_idx(wc * 64 + (n + 2) * 16 + frc, cb)];
    if (st) stage_half(Ag, arow, kn + 32, lda, nA1, wave, lane, 1);
    BARRIER;
    __builtin_amdgcn_s_setprio(1);
#pragma unroll
    for (int m = 0; m < 4; ++m)
#pragma unroll
      for (int n = 0; n < 2; ++n)
        acc[m][n + 2] = __builtin_amdgcn_mfma_f32_16x16x32_f16(af[m], bf1[n], acc[m][n + 2], 0, 0, 0);
    __builtin_amdgcn_s_setprio(0);
    BARRIER;
    // ph7: Q(1,0) + stage B(kt1) half0
#pragma unroll
    for (int m = 0; m < 4; ++m)
      af[m] = *(const half8*)&a1[swz_idx(wr * 128 + 64 + m * 16 + frc, cb)];
    if (st) stage_half(Bg, brow, kn + 32, ldb, nB1, wave, lane, 0);
    BARRIER;
    __builtin_amdgcn_s_setprio(1);
#pragma unroll
    for (int m = 0; m < 4; ++m)
#pragma unroll
      for (int n = 0; n < 2; ++n)
        acc[m + 4][n] = __builtin_amdgcn_mfma_f32_16x16x32_f16(af[m], bf0[n], acc[m + 4][n], 0, 0, 0);
    __builtin_amdgcn_s_setprio(0);
    BARRIER;
    // ph8: Q(1,1) + stage B(kt1) half1 + counted wait (next kt0 resident)
    if (st) {
      stage_half(Bg, brow, kn + 32, ldb, nB1, wave, lane, 1);
      asm volatile("s_waitcnt vmcnt(4)" ::: "memory");
    }
    BARRIER;
    __builtin_amdgcn_s_setprio(1);
#pragma unroll
    for (int m = 0; m < 4; ++m)
#pragma unroll
      for (int n = 0; n < 2; ++n)
        acc[m + 4][n + 2] = __builtin_amdgcn_mfma_f32_16x16x32_f16(af[m], bf1[n], acc[m + 4][n + 2], 0, 0, 0);
    __builtin_amdgcn_s_setprio(0);
    BARRIER;
  }

  // ---- epilogue; D mapping: col = lane&15, row = (lane>>4)*4 + i ----
  const int koff = half ? 1024 : 0;
  if (MODE == 0) {
    unsigned short* Tt = (unsigned short*)outp;
#pragma unroll
    for (int mi = 0; mi < 8; ++mi) {
      const int r = bm + wr * 128 + (mi >> 2) * 64 + (mi & 3) * 16 + (lane >> 4) * 4;
      const int b = r >> 11;
      const int rb = r & 2047;
#pragma unroll
      for (int n = 0; n < 4; ++n) {
        const int cpk = bn + wc * 64 + n * 16 + frc;
        const int ktrue = 2 * (cpk - koff) + (half ? 1 : 0);
        uint32 lo = f2h_bits(acc[mi][n][0]) | ((uint32)f2h_bits(acc[mi][n][1]) << 16);
        uint32 hi = f2h_bits(acc[mi][n][2]) | ((uint32)f2h_bits(acc[mi][n][3]) << 16);
        *(uint2*)&Tt[(size_t)b * 4194304 + (size_t)ktrue * 2048 + rb] =
            make_uint2(lo, hi);
      }
    }
  } else {
    float* out = (float*)outp + (size_t)z * 4194304;
#pragma unroll
    for (int mi = 0; mi < 8; ++mi) {
      const int p0 =
          bm + wr * 128 + (mi >> 2) * 64 + (mi & 3) * 16 + (lane >> 4) * 4 - koff;
#pragma unroll
      for (int n = 0; n < 4; ++n) {
        const int cg = bn + wc * 64 + n * 16 + frc;
#pragma unroll
        for (int i = 0; i < 4; ++i) {
          const int rtrue = 2 * (p0 + i) + (half ? 1 : 0);
          out[(size_t)rtrue * 2048 + cg] = acc[mi][n][i];
        }
      }
    }
  }
}

extern "C" void kernel_launch(void* const* d_in, const int* in_sizes, int n_in,
                              void* d_out, int out_size, void* d_ws,
                              size_t ws_size, hipStream_t stream) {
  const float* x = (const float*)d_in[0];
  float* out = (float*)d_out;

  // workspace (f16 elems): Xf/U2 33554432 | Ce 1048576 | Co 1048576 | Tt 33554432
  unsigned short* Xf = (unsigned short*)d_ws;  // aliased as U2 after GEMM1
  unsigned short* Ce = Xf + 33554432u;
  unsigned short* Co = Ce + 1048576u;
  unsigned short* Tt = Co + 1048576u;

  cvt_fold1<<<8192, 256, 0, stream>>>(x, Xf);
  gen_cos2<<<4096, 256, 0, stream>>>(Ce, Co);
  // stage 1: T over folded K=1024; writes Tt[b][k_true][m] (f16)
  dct_gemm<0><<<dim3(8, 64, 1), 512, 0, stream>>>(Ce, Co, Xf, (void*)Tt);
  // stage 2 fold along m (Xf region reused as U2)
  fold2<<<8192, 256, 0, stream>>>(Tt, Xf);
  // stage 2: out[b] rows parity-unpacked, fp32
  dct_gemm<1><<<dim3(8, 8, 8), 512, 0, stream>>>(Ce, Co, Xf, (void*)out);
}

// Round 7
// 208.511 us; speedup vs baseline: 6.4038x; 1.1397x over previous
//
#include <hip/hip_runtime.h>
#include <hip/hip_bf16.h>
#include <hip/hip_fp16.h>

// 2D DCT-II via double-folded (even/odd x even/odd) f16 MFMA GEMMs.
// Key identity: the stage-2 row-fold commutes with stage-1's column GEMM,
// so BOTH folds are applied in the f32 convert kernel (cvt_fold12):
//   Xff[b,ui][uj]        = S_i S_j x   (even-row, even-col quarter)
//   Xff[b,ui][1024+uj]   = S_i D_j x
//   Xff[b,1024+ui][uj]   = D_i S_j x
//   Xff[b,1024+ui][1024+uj] = D_i D_j x
// GEMM1 (unchanged R4 structure, 88us proven): T'= Xff x [Ce|Co]^T, output
// transposed per batch -> exactly the old U2. GEMM2 (unchanged): out = C x T'.
// fold2 kernel deleted (-21us of HBM round-trip).

typedef _Float16 half8 __attribute__((ext_vector_type(8)));
typedef float f32x4 __attribute__((ext_vector_type(4)));
typedef unsigned int uint32;

constexpr int BK = 32;
constexpr int BM = 256, BN = 256;
constexpr int KK = 1024;          // folded GEMM K
constexpr int NT = KK / BK;       // 32 K-tiles
constexpr int TILE_E = BM * BK;   // 8192 f16 = 16KB

__device__ __forceinline__ unsigned short f2h_bits(float f) {
  _Float16 h = (_Float16)f;
  return __builtin_bit_cast(unsigned short, h);
}

__device__ __forceinline__ void gload_lds16(const unsigned short* g, unsigned short* l) {
  __builtin_amdgcn_global_load_lds((const __attribute__((address_space(1))) void*)g,
                                   (__attribute__((address_space(3))) void*)l,
                                   16, 0, 0);
}

#define CFENCE asm volatile("" ::: "memory")

// Stored f16 index for logical (tile row r, 16B k-slot byte cb); stored rows
// are 128B (two logical rows); slot' = ((r&1)<<2 | cb>>4) ^ ((r>>1)&7).
// Measured 0 bank conflicts (R2-R4).
__device__ __forceinline__ int swz_idx(int r, int cbyte) {
  int b = (r >> 1) * 128 + ((((r & 1) << 6) | cbyte) ^ (((r >> 1) & 7) << 4));
  return b >> 1;
}

// Stage a 256x32 f16 tile from G (row-major, stride ld); LDS dest LINEAR,
// swizzle realized by inverse-permuting per-lane global source addresses.
__device__ __forceinline__ void stage_tile(const unsigned short* __restrict__ G,
                                           int rowbase, int k0, int ld,
                                           unsigned short* lds, int wave, int lane) {
#pragma unroll
  for (int c = 0; c < 2; ++c) {
    const int p = c * 64 + wave * 8 + (lane >> 3);   // stored 128B row
    const int v = (lane & 7) ^ ((lane >> 3) & 7);    // inverse slot swizzle
    const int r = 2 * p + (v >> 2);                  // logical tile row
    const int kslot = v & 3;
    const unsigned short* src = G + (size_t)(rowbase + r) * ld + (k0 + kslot * 8);
    unsigned short* dst = lds + (c * 64 + wave * 8) * 64;  // wave-uniform
    gload_lds16(src, dst);
  }
}

// ---- convert + BOTH folds (f32 in, f16 quarters out) ------------------------
// thread: (b, ui, j-chunk). Reads rows i=ui and i'=2047-ui of image b at cols
// [j0,j0+8) and [2040-j0,2048-j0). Emits 4x uint4 (8 f16 each).
__global__ __launch_bounds__(256) void cvt_fold12(const float* __restrict__ x,
                                                  unsigned short* __restrict__ Xff) {
  int tid = blockIdx.x * 256 + threadIdx.x;   // 1M threads
  int m = tid >> 7;                           // b*1024 + ui, [0, 8192)
  int b = m >> 10;
  int ui = m & 1023;
  int j0 = (tid & 127) << 3;                  // 0..1016
  const float* rf = x + ((size_t)b * 2048 + ui) * 2048;
  const float* rb = x + ((size_t)b * 2048 + 2047 - ui) * 2048;
  float4 fa = *(const float4*)(rf + j0);
  float4 fb = *(const float4*)(rf + j0 + 4);
  float4 fc = *(const float4*)(rf + 2040 - j0);
  float4 fd = *(const float4*)(rf + 2044 - j0);
  float4 ga = *(const float4*)(rb + j0);
  float4 gb = *(const float4*)(rb + j0 + 4);
  float4 gc = *(const float4*)(rb + 2040 - j0);
  float4 gd = *(const float4*)(rb + 2044 - j0);
  float f[8] = {fa.x, fa.y, fa.z, fa.w, fb.x, fb.y, fb.z, fb.w};
  float fm[8] = {fd.w, fd.z, fd.y, fd.x, fc.w, fc.z, fc.y, fc.x};  // rf[2047-j]
  float g[8] = {ga.x, ga.y, ga.z, ga.w, gb.x, gb.y, gb.z, gb.w};
  float gm[8] = {gd.w, gd.z, gd.y, gd.x, gc.w, gc.z, gc.y, gc.x};  // rb[2047-j]
  uint32 ss[4], sd[4], ds[4], dd[4];
#pragma unroll
  for (int e = 0; e < 4; ++e) {
#pragma unroll
    for (int h = 0; h < 2; ++h) {
      int k = 2 * e + h;
      float fs = f[k] + fm[k], fdv = f[k] - fm[k];
      float gs = g[k] + gm[k], gdv = g[k] - gm[k];
      uint32 vss = f2h_bits(fs + gs), vsd = f2h_bits(fdv + gdv);
      uint32 vds = f2h_bits(fs - gs), vdd = f2h_bits(fdv - gdv);
      if (h == 0) { ss[e] = vss; sd[e] = vsd; ds[e] = vds; dd[e] = vdd; }
      else { ss[e] |= vss << 16; sd[e] |= vsd << 16; ds[e] |= vds << 16; dd[e] |= vdd << 16; }
    }
  }
  unsigned short* os = Xff + ((size_t)b * 2048 + ui) * 2048 + j0;
  unsigned short* od = Xff + ((size_t)b * 2048 + 1024 + ui) * 2048 + j0;
  *(uint4*)os = make_uint4(ss[0], ss[1], ss[2], ss[3]);
  *(uint4*)(os + 1024) = make_uint4(sd[0], sd[1], sd[2], sd[3]);
  *(uint4*)od = make_uint4(ds[0], ds[1], ds[2], ds[3]);
  *(uint4*)(od + 1024) = make_uint4(dd[0], dd[1], dd[2], dd[3]);
}

// ---- even/odd cosine matrices, 1024x1024 each -------------------------------
// Ce[k][n] = cos(pi*(2n+1)*(2k)/4096), Co[k][n] = cos(pi*(2n+1)*(2k+1)/4096)
__global__ __launch_bounds__(256) void gen_cos2(unsigned short* __restrict__ Ce,
                                                unsigned short* __restrict__ Co) {
  int idx = blockIdx.x * 256 + threadIdx.x;  // 1M
  int k = idx >> 10, n = idx & 1023;
  int tn = 2 * n + 1;
  int pe = (tn * (2 * k)) & 8191;
  int po = (tn * (2 * k + 1)) & 8191;
  const float s = 7.6699039394282061e-4f;  // pi/4096
  Ce[idx] = f2h_bits(cosf((float)pe * s));
  Co[idx] = f2h_bits(cosf((float)po * s));
}

// ---- pipelined GEMM, K=1024, 4-buffer ring (R4-proven, 88us) ----------------
// MODE 0: A = Xff (col half by bn), B = Ce/Co; OUT f16 transposed into
//         U2t[b][k_true][m2]. MODE 1: A = Ce/Co, B = U2t[z]; OUT fp32
//         row-major at parity-unpacked row.
template <int MODE>
__global__ __launch_bounds__(512) void dct_gemm(
    const unsigned short* __restrict__ Ce, const unsigned short* __restrict__ Co,
    const unsigned short* __restrict__ D, void* __restrict__ outp) {
  __shared__ unsigned short As[4 * TILE_E];
  __shared__ unsigned short Bs[4 * TILE_E];

  const int tid = threadIdx.x;
  const int lane = tid & 63;
  const int wave = tid >> 6;
  const int wr = wave >> 2;
  const int wc = wave & 3;
  const int bm = blockIdx.y * BM;
  const int bn = blockIdx.x * BN;
  const int z = blockIdx.z;

  const unsigned short* Ag;
  const unsigned short* Bg;
  int lda, ldb, arow, brow;
  bool half;
  if (MODE == 0) {
    half = (bn >= 1024);
    Ag = D + (half ? 1024 : 0); lda = 2048; arow = bm;
    Bg = half ? Co : Ce;        ldb = 1024; brow = bn - (half ? 1024 : 0);
  } else {
    half = (bm >= 1024);
    Ag = half ? Co : Ce;        lda = 1024; arow = bm - (half ? 1024 : 0);
    Bg = D + (size_t)z * 4194304u + (half ? 1024 : 0);
    ldb = 2048; brow = bn;
  }

  const int frc = lane & 15;
  const int cb = (lane >> 4) << 4;

  f32x4 acc[8][4] = {};

  stage_tile(Ag, arow, 0, lda, &As[0], wave, lane);
  stage_tile(Bg, brow, 0, ldb, &Bs[0], wave, lane);
  stage_tile(Ag, arow, BK, lda, &As[TILE_E], wave, lane);
  stage_tile(Bg, brow, BK, ldb, &Bs[TILE_E], wave, lane);
  asm volatile("s_waitcnt vmcnt(4)" ::: "memory");
  CFENCE; __builtin_amdgcn_s_barrier(); CFENCE;

  for (int t = 0; t < NT; ++t) {
    const unsigned short* at = &As[(t & 3) * TILE_E];
    const unsigned short* bt = &Bs[(t & 3) * TILE_E];
    half8 af[4], bf[4];

    // phase 1: reads (quadrant mh=0) + stage A(t+2)
#pragma unroll
    for (int m = 0; m < 4; ++m)
      af[m] = *(const half8*)&at[swz_idx(wr * 128 + m * 16 + frc, cb)];
#pragma unroll
    for (int n = 0; n < 4; ++n)
      bf[n] = *(const half8*)&bt[swz_idx(wc * 64 + n * 16 + frc, cb)];
    if (t + 2 < NT)
      stage_tile(Ag, arow, (t + 2) * BK, lda, &As[((t + 2) & 3) * TILE_E], wave, lane);
    CFENCE; __builtin_amdgcn_s_barrier(); CFENCE;
    __builtin_amdgcn_s_setprio(1);
#pragma unroll
    for (int m = 0; m < 4; ++m)
#pragma unroll
      for (int n = 0; n < 4; ++n)
        acc[m][n] = __builtin_amdgcn_mfma_f32_16x16x32_f16(af[m], bf[n], acc[m][n], 0, 0, 0);
    __builtin_amdgcn_s_setprio(0);

    // phase 2: reads (quadrant mh=1) + stage B(t+2) + counted boundary
#pragma unroll
    for (int m = 0; m < 4; ++m)
      af[m] = *(const half8*)&at[swz_idx(wr * 128 + 64 + m * 16 + frc, cb)];
    if (t + 2 < NT)
      stage_tile(Bg, brow, (t + 2) * BK, ldb, &Bs[((t + 2) & 3) * TILE_E], wave, lane);
    if (t < NT - 2)
      asm volatile("s_waitcnt vmcnt(4)" ::: "memory");
    else if (t == NT - 2)
      asm volatile("s_waitcnt vmcnt(0)" ::: "memory");
    CFENCE; __builtin_amdgcn_s_barrier(); CFENCE;
    __builtin_amdgcn_s_setprio(1);
#pragma unroll
    for (int m = 0; m < 4; ++m)
#pragma unroll
      for (int n = 0; n < 4; ++n)
        acc[m + 4][n] =
            __builtin_amdgcn_mfma_f32_16x16x32_f16(af[m], bf[n], acc[m + 4][n], 0, 0, 0);
    __builtin_amdgcn_s_setprio(0);
  }

  // epilogue; D mapping: col = lane&15, row = (lane>>4)*4 + i
  const int koff = half ? 1024 : 0;
  if (MODE == 0) {
    unsigned short* U2t = (unsigned short*)outp;
#pragma unroll
    for (int mi = 0; mi < 8; ++mi) {
      const int r = bm + wr * 128 + (mi >> 2) * 64 + (mi & 3) * 16 + (lane >> 4) * 4;
      const int b = r >> 11;
      const int rb = r & 2047;
#pragma unroll
      for (int n = 0; n < 4; ++n) {
        const int cpk = bn + wc * 64 + n * 16 + frc;
        const int ktrue = 2 * (cpk - koff) + (half ? 1 : 0);
        uint32 lo = f2h_bits(acc[mi][n][0]) | ((uint32)f2h_bits(acc[mi][n][1]) << 16);
        uint32 hi = f2h_bits(acc[mi][n][2]) | ((uint32)f2h_bits(acc[mi][n][3]) << 16);
        *(uint2*)&U2t[(size_t)b * 4194304 + (size_t)ktrue * 2048 + rb] =
            make_uint2(lo, hi);
      }
    }
  } else {
    float* out = (float*)outp + (size_t)z * 4194304;
#pragma unroll
    for (int mi = 0; mi < 8; ++mi) {
      const int p0 =
          bm + wr * 128 + (mi >> 2) * 64 + (mi & 3) * 16 + (lane >> 4) * 4 - koff;
#pragma unroll
      for (int n = 0; n < 4; ++n) {
        const int cg = bn + wc * 64 + n * 16 + frc;
#pragma unroll
        for (int i = 0; i < 4; ++i) {
          const int rtrue = 2 * (p0 + i) + (half ? 1 : 0);
          out[(size_t)rtrue * 2048 + cg] = acc[mi][n][i];
        }
      }
    }
  }
}

extern "C" void kernel_launch(void* const* d_in, const int* in_sizes, int n_in,
                              void* d_out, int out_size, void* d_ws,
                              size_t ws_size, hipStream_t stream) {
  const float* x = (const float*)d_in[0];
  float* out = (float*)d_out;

  // workspace (f16 elems): Xff 33554432 | Ce 1048576 | Co 1048576 | U2t 33554432
  unsigned short* Xff = (unsigned short*)d_ws;
  unsigned short* Ce = Xff + 33554432u;
  unsigned short* Co = Ce + 1048576u;
  unsigned short* U2t = Co + 1048576u;

  cvt_fold12<<<4096, 256, 0, stream>>>(x, Xff);
  gen_cos2<<<4096, 256, 0, stream>>>(Ce, Co);
  // stage 1: U2t[b][ktrue][m2] = (double-folded X) x [Ce|Co]^T, transposed
  dct_gemm<0><<<dim3(8, 64, 1), 512, 0, stream>>>(Ce, Co, Xff, (void*)U2t);
  // stage 2: out[b] rows parity-unpacked, fp32
  dct_gemm<1><<<dim3(8, 8, 8), 512, 0, stream>>>(Ce, Co, U2t, (void*)out);
}

// Round 8
// 207.032 us; speedup vs baseline: 6.4495x; 1.0071x over previous
//
#include <hip/hip_runtime.h>
#include <hip/hip_bf16.h>
#include <hip/hip_fp16.h>

// 2D DCT-II via LEVEL-2 folded f16 MFMA GEMMs.
// Per 2048-DCT: k odd -> DCT4-1024 on w (K=1024); k=4s -> DCT2-512 on u+
// (K=512); k=4s+2 -> DCT4-512 on u- (K=512). MACs = 0.75x of level-1.
// Both dims' folds (2 levels each) are applied in cvt_fold22 (f32, fused);
// no inter-GEMM fold pass. Xff row layout per batch: [Sp 512 | Sm 512 | D 1024];
// col layout per row: [u+ 512 | u- 512 | w 1024]. Stage-1 output U2t[b][k][m2]
// (transposed f16) feeds stage 2 directly with the same 3-way row split.
// GEMM inner loop = R4/R7 proven structure (byte-identical): 256x256 tile,
// BK=32, 8 waves, 4-buffer LDS ring, counted vmcnt(4), XOR swizzle, setprio.

typedef _Float16 half8 __attribute__((ext_vector_type(8)));
typedef float f32x4 __attribute__((ext_vector_type(4)));
typedef unsigned int uint32;

constexpr int TILE_E = 256 * 32;  // 8192 f16 = 16KB

__device__ __forceinline__ unsigned short f2h_bits(float f) {
  _Float16 h = (_Float16)f;
  return __builtin_bit_cast(unsigned short, h);
}

__device__ __forceinline__ void gload_lds16(const unsigned short* g, unsigned short* l) {
  __builtin_amdgcn_global_load_lds((const __attribute__((address_space(1))) void*)g,
                                   (__attribute__((address_space(3))) void*)l,
                                   16, 0, 0);
}

#define CFENCE asm volatile("" ::: "memory")

// Stored f16 index for logical (tile row r, 16B k-slot byte cb); stored rows
// are 128B (two logical rows); slot' = ((r&1)<<2 | cb>>4) ^ ((r>>1)&7).
// Measured 0 bank conflicts (R2-R7).
__device__ __forceinline__ int swz_idx(int r, int cbyte) {
  int b = (r >> 1) * 128 + ((((r & 1) << 6) | cbyte) ^ (((r >> 1) & 7) << 4));
  return b >> 1;
}

// Stage a 256x32 f16 tile from G (row-major, stride ld); LDS dest LINEAR,
// swizzle realized by inverse-permuting per-lane global source addresses.
__device__ __forceinline__ void stage_tile(const unsigned short* __restrict__ G,
                                           int rowbase, int k0, int ld,
                                           unsigned short* lds, int wave, int lane) {
#pragma unroll
  for (int c = 0; c < 2; ++c) {
    const int p = c * 64 + wave * 8 + (lane >> 3);   // stored 128B row
    const int v = (lane & 7) ^ ((lane >> 3) & 7);    // inverse slot swizzle
    const int r = 2 * p + (v >> 2);                  // logical tile row
    const int kslot = v & 3;
    const unsigned short* src = G + (size_t)(rowbase + r) * ld + (k0 + kslot * 8);
    unsigned short* dst = lds + (c * 64 + wave * 8) * 64;  // wave-uniform
    gload_lds16(src, dst);
  }
}

// ---- convert + FULL 2-level 2D fold (f32 in, f16 out) -----------------------
// Thread (b, v<512, j0<512): reads x-rows {v, 2047-v, 1023-v, 1024+v} at col
// groups {j0.., 1023-j0.., 1024+j0.., 2047-j0..}; emits 4 output rows
// {v (Sp), 512+v (Sm), 1024+v (D_v), 2047-v (D_{1023-v})} x 4 col chunks
// {j0 (u+), 512+j0 (u-), 1024+j0 (w_n), rev (w_m)}.
__global__ __launch_bounds__(256) void cvt_fold22(const float* __restrict__ x,
                                                  unsigned short* __restrict__ Xff) {
  int tid = blockIdx.x * 256 + threadIdx.x;   // 262144 threads
  int m = tid >> 6;                           // b*512 + v
  int b = m >> 9;
  int v = m & 511;
  int j0 = (tid & 63) << 3;                   // [0,512)
  const float* base = x + (size_t)b * 4194304;
  const float* rows[4] = {base + (size_t)v * 2048, base + (size_t)(2047 - v) * 2048,
                          base + (size_t)(1023 - v) * 2048, base + (size_t)(1024 + v) * 2048};
  unsigned short* o[4] = {
      Xff + ((size_t)b * 2048 + v) * 2048,          // Sp
      Xff + ((size_t)b * 2048 + 512 + v) * 2048,    // Sm
      Xff + ((size_t)b * 2048 + 1024 + v) * 2048,   // D_v
      Xff + ((size_t)b * 2048 + 2047 - v) * 2048};  // D_{1023-v}

#pragma unroll
  for (int h = 0; h < 2; ++h) {
    const int ja = j0 + h * 4;          // A: cols ja..ja+3
    const int jb = 1020 - j0 - h * 4;   // B: cols jb..jb+3 (reversed use)
    const int jc = 1024 + j0 + h * 4;   // C
    const int jd = 2044 - j0 - h * 4;   // D (reversed use)
    float4 va[4], vb[4], vc[4], vd[4];
#pragma unroll
    for (int t = 0; t < 4; ++t) {
      va[t] = *(const float4*)(rows[t] + ja);
      vb[t] = *(const float4*)(rows[t] + jb);
      vc[t] = *(const float4*)(rows[t] + jc);
      vd[t] = *(const float4*)(rows[t] + jd);
    }
    unsigned short up[4][4], um[4][4], wn[4][4], wm[4][4];
#pragma unroll
    for (int e4 = 0; e4 < 4; ++e4) {
      float A[4], Bq[4], C[4], Dq[4];
#pragma unroll
      for (int t = 0; t < 4; ++t) {
        A[t] = ((const float*)&va[t])[e4];        // x[row][ja+e4]
        Bq[t] = ((const float*)&vb[t])[3 - e4];   // x[row][1023-j0-h4-e4]
        C[t] = ((const float*)&vc[t])[e4];        // x[row][1024+ja'+e4]
        Dq[t] = ((const float*)&vd[t])[3 - e4];   // x[row][2047-j0-h4-e4]
      }
      // row combos: vrow0=Sp=(r0+r1)+(r2+r3); 1=Sm=(r0+r1)-(r2+r3); 2=r0-r1; 3=r2-r3
      float Av[4] = {A[0] + A[1] + A[2] + A[3], A[0] + A[1] - A[2] - A[3],
                     A[0] - A[1], A[2] - A[3]};
      float Bv[4] = {Bq[0] + Bq[1] + Bq[2] + Bq[3], Bq[0] + Bq[1] - Bq[2] - Bq[3],
                     Bq[0] - Bq[1], Bq[2] - Bq[3]};
      float Cv[4] = {C[0] + C[1] + C[2] + C[3], C[0] + C[1] - C[2] - C[3],
                     C[0] - C[1], C[2] - C[3]};
      float Dv[4] = {Dq[0] + Dq[1] + Dq[2] + Dq[3], Dq[0] + Dq[1] - Dq[2] - Dq[3],
                     Dq[0] - Dq[1], Dq[2] - Dq[3]};
#pragma unroll
      for (int t = 0; t < 4; ++t) {
        float un = Av[t] + Dv[t];   // u[n]
        float umr = Bv[t] + Cv[t];  // u[1023-n]
        up[t][e4] = f2h_bits(un + umr);
        um[t][e4] = f2h_bits(un - umr);
        wn[t][e4] = f2h_bits(Av[t] - Dv[t]);   // w[n]
        wm[t][e4] = f2h_bits(Bv[t] - Cv[t]);   // w[1023-n]
      }
    }
#pragma unroll
    for (int t = 0; t < 4; ++t) {
      *(uint2*)(o[t] + ja) =
          make_uint2(up[t][0] | ((uint32)up[t][1] << 16), up[t][2] | ((uint32)up[t][3] << 16));
      *(uint2*)(o[t] + 512 + ja) =
          make_uint2(um[t][0] | ((uint32)um[t][1] << 16), um[t][2] | ((uint32)um[t][3] << 16));
      *(uint2*)(o[t] + 1024 + ja) =
          make_uint2(wn[t][0] | ((uint32)wn[t][1] << 16), wn[t][2] | ((uint32)wn[t][3] << 16));
      // w_m reversed: col 1024+jb+e' holds wm[3-e']
      *(uint2*)(o[t] + 1024 + jb) =
          make_uint2(wm[t][3] | ((uint32)wm[t][2] << 16), wm[t][1] | ((uint32)wm[t][0] << 16));
    }
  }
}

// ---- cosine matrices: C4k 1024x1024 (DCT-IV), C2h 512x512, C4h 512x512 ------
__global__ __launch_bounds__(256) void gen_cos3(unsigned short* __restrict__ C4k,
                                                unsigned short* __restrict__ C2h,
                                                unsigned short* __restrict__ C4h) {
  int idx = blockIdx.x * 256 + threadIdx.x;  // 1572864
  const float s = 7.6699039394282061e-4f;    // pi/4096
  if (idx < 1048576) {
    int k = idx >> 10, n = idx & 1023;
    int t = ((2 * n + 1) * (2 * k + 1)) & 8191;   // cos(pi(2n+1)(2k+1)/4096)
    C4k[idx] = f2h_bits(cosf((float)t * s));
  } else if (idx < 1310720) {
    int i2 = idx - 1048576;
    int k = i2 >> 9, n = i2 & 511;
    int t = ((2 * n + 1) * 4 * k) & 8191;         // cos(pi(2n+1)k/1024)
    C2h[i2] = f2h_bits(cosf((float)t * s));
  } else {
    int i2 = idx - 1310720;
    int k = i2 >> 9, n = i2 & 511;
    int t = ((2 * n + 1) * (4 * k + 2)) & 8191;   // cos(pi(2n+1)(2k+1)/2048)
    C4h[i2] = f2h_bits(cosf((float)t * s));
  }
}

// ---- pipelined GEMM (R4/R7-proven inner loop) -------------------------------
// MODE 0 (stage 1, f16 transposed out U2t[b][ktrue][m2]):
//   SPLIT 0: A cols [1024,2048)=w, B=M0=C4k,  K=1024, ktrue=2c+1
//   SPLIT 1: cls=bn>>1: A cols cls*512 (u+/u-), B=C2h/C4h, K=512, ktrue=4c+2cls
// MODE 1 (stage 2, fp32 out):
//   SPLIT 0: A=C4k (M=1024), B=U2t[z] cols [1024,2048), K=1024, rtrue=2p+1
//   SPLIT 1: cls=by>>1: A=C2h/C4h, B=U2t[z] cols cls*512, K=512, rtrue=4p+2cls
template <int MODE, int SPLIT>
__global__ __launch_bounds__(512) void dct_gemm(
    const unsigned short* __restrict__ M0, const unsigned short* __restrict__ M1,
    const unsigned short* __restrict__ D, void* __restrict__ outp) {
  constexpr int K = SPLIT ? 512 : 1024;
  constexpr int NT = K / 32;
  __shared__ unsigned short As[4 * TILE_E];
  __shared__ unsigned short Bs[4 * TILE_E];

  const int tid = threadIdx.x;
  const int lane = tid & 63;
  const int wave = tid >> 6;
  const int wr = wave >> 2;
  const int wc = wave & 3;
  const int bmx = blockIdx.y;
  const int bnx = blockIdx.x;
  const int z = blockIdx.z;

  const unsigned short* Ag;
  const unsigned short* Bg;
  int lda, ldb, arow, brow, cls;
  if (MODE == 0) {
    cls = SPLIT ? (bnx >> 1) : 0;
    Ag = D + (SPLIT ? cls * 512 : 1024);
    lda = 2048;
    arow = bmx * 256;
    Bg = SPLIT ? (cls ? M1 : M0) : M0;
    ldb = K;
    brow = (SPLIT ? (bnx & 1) : bnx) * 256;
  } else {
    cls = SPLIT ? (bmx >> 1) : 0;
    Ag = SPLIT ? (cls ? M1 : M0) : M0;
    lda = K;
    arow = (SPLIT ? (bmx & 1) : bmx) * 256;
    Bg = D + (size_t)z * 4194304u + (SPLIT ? cls * 512 : 1024);
    ldb = 2048;
    brow = bnx * 256;
  }

  const int frc = lane & 15;
  const int cb = (lane >> 4) << 4;

  f32x4 acc[8][4] = {};

  stage_tile(Ag, arow, 0, lda, &As[0], wave, lane);
  stage_tile(Bg, brow, 0, ldb, &Bs[0], wave, lane);
  stage_tile(Ag, arow, 32, lda, &As[TILE_E], wave, lane);
  stage_tile(Bg, brow, 32, ldb, &Bs[TILE_E], wave, lane);
  asm volatile("s_waitcnt vmcnt(4)" ::: "memory");
  CFENCE; __builtin_amdgcn_s_barrier(); CFENCE;

  for (int t = 0; t < NT; ++t) {
    const unsigned short* at = &As[(t & 3) * TILE_E];
    const unsigned short* bt = &Bs[(t & 3) * TILE_E];
    half8 af[4], bf[4];

    // phase 1: reads (quadrant mh=0) + stage A(t+2)
#pragma unroll
    for (int m = 0; m < 4; ++m)
      af[m] = *(const half8*)&at[swz_idx(wr * 128 + m * 16 + frc, cb)];
#pragma unroll
    for (int n = 0; n < 4; ++n)
      bf[n] = *(const half8*)&bt[swz_idx(wc * 64 + n * 16 + frc, cb)];
    if (t + 2 < NT)
      stage_tile(Ag, arow, (t + 2) * 32, lda, &As[((t + 2) & 3) * TILE_E], wave, lane);
    CFENCE; __builtin_amdgcn_s_barrier(); CFENCE;
    __builtin_amdgcn_s_setprio(1);
#pragma unroll
    for (int m = 0; m < 4; ++m)
#pragma unroll
      for (int n = 0; n < 4; ++n)
        acc[m][n] = __builtin_amdgcn_mfma_f32_16x16x32_f16(af[m], bf[n], acc[m][n], 0, 0, 0);
    __builtin_amdgcn_s_setprio(0);

    // phase 2: reads (quadrant mh=1) + stage B(t+2) + counted boundary
#pragma unroll
    for (int m = 0; m < 4; ++m)
      af[m] = *(const half8*)&at[swz_idx(wr * 128 + 64 + m * 16 + frc, cb)];
    if (t + 2 < NT)
      stage_tile(Bg, brow, (t + 2) * 32, ldb, &Bs[((t + 2) & 3) * TILE_E], wave, lane);
    if (t < NT - 2)
      asm volatile("s_waitcnt vmcnt(4)" ::: "memory");
    else if (t == NT - 2)
      asm volatile("s_waitcnt vmcnt(0)" ::: "memory");
    CFENCE; __builtin_amdgcn_s_barrier(); CFENCE;
    __builtin_amdgcn_s_setprio(1);
#pragma unroll
    for (int m = 0; m < 4; ++m)
#pragma unroll
      for (int n = 0; n < 4; ++n)
        acc[m + 4][n] =
            __builtin_amdgcn_mfma_f32_16x16x32_f16(af[m], bf[n], acc[m + 4][n], 0, 0, 0);
    __builtin_amdgcn_s_setprio(0);
  }

  // epilogue; D mapping: col = lane&15, row = (lane>>4)*4 + i
  if (MODE == 0) {
    unsigned short* U2t = (unsigned short*)outp;
#pragma unroll
    for (int mi = 0; mi < 8; ++mi) {
      const int r = arow + wr * 128 + (mi >> 2) * 64 + (mi & 3) * 16 + (lane >> 4) * 4;
      const int b = r >> 11;
      const int rb = r & 2047;
#pragma unroll
      for (int n = 0; n < 4; ++n) {
        const int ccls = brow + wc * 64 + n * 16 + frc;
        const int ktrue = SPLIT ? (4 * ccls + 2 * cls) : (2 * ccls + 1);
        uint32 lo = f2h_bits(acc[mi][n][0]) | ((uint32)f2h_bits(acc[mi][n][1]) << 16);
        uint32 hi = f2h_bits(acc[mi][n][2]) | ((uint32)f2h_bits(acc[mi][n][3]) << 16);
        *(uint2*)&U2t[(size_t)b * 4194304 + (size_t)ktrue * 2048 + rb] =
            make_uint2(lo, hi);
      }
    }
  } else {
    float* out = (float*)outp + (size_t)z * 4194304;
#pragma unroll
    for (int mi = 0; mi < 8; ++mi) {
      const int p0 = arow + wr * 128 + (mi >> 2) * 64 + (mi & 3) * 16 + (lane >> 4) * 4;
#pragma unroll
      for (int n = 0; n < 4; ++n) {
        const int cg = brow + wc * 64 + n * 16 + frc;
#pragma unroll
        for (int i = 0; i < 4; ++i) {
          const int rtrue = SPLIT ? (4 * (p0 + i) + 2 * cls) : (2 * (p0 + i) + 1);
          out[(size_t)rtrue * 2048 + cg] = acc[mi][n][i];
        }
      }
    }
  }
}

extern "C" void kernel_launch(void* const* d_in, const int* in_sizes, int n_in,
                              void* d_out, int out_size, void* d_ws,
                              size_t ws_size, hipStream_t stream) {
  const float* x = (const float*)d_in[0];
  float* out = (float*)d_out;

  // workspace (f16 elems):
  // Xff 33554432 | C4k 1048576 | C2h 262144 | C4h 262144 | U2t 33554432
  unsigned short* Xff = (unsigned short*)d_ws;
  unsigned short* C4k = Xff + 33554432u;
  unsigned short* C2h = C4k + 1048576u;
  unsigned short* C4h = C2h + 262144u;
  unsigned short* U2t = C4h + 262144u;

  cvt_fold22<<<1024, 256, 0, stream>>>(x, Xff);
  gen_cos3<<<6144, 256, 0, stream>>>(C4k, C2h, C4h);
  // stage 1: odd k (K=1024) and even k (K=512, u+/u- classes)
  dct_gemm<0, 0><<<dim3(4, 64, 1), 512, 0, stream>>>(C4k, C4k, Xff, (void*)U2t);
  dct_gemm<0, 1><<<dim3(4, 64, 1), 512, 0, stream>>>(C2h, C4h, Xff, (void*)U2t);
  // stage 2: odd rows (K=1024) and even rows (K=512)
  dct_gemm<1, 0><<<dim3(8, 4, 8), 512, 0, stream>>>(C4k, C4k, U2t, (void*)out);
  dct_gemm<1, 1><<<dim3(8, 4, 8), 512, 0, stream>>>(C2h, C4h, U2t, (void*)out);
}

// Round 9
// 196.911 us; speedup vs baseline: 6.7810x; 1.0514x over previous
//
#include <hip/hip_runtime.h>
#include <hip/hip_bf16.h>
#include <hip/hip_fp16.h>

// 2D DCT-II via LEVEL-2 folded f16 MFMA GEMMs.
// Per 2048-DCT: k odd -> DCT4-1024 on w (K=1024); k=4s -> DCT2-512 on u+
// (K=512); k=4s+2 -> DCT4-512 on u- (K=512). MACs = 0.75x of level-1.
// Both dims' folds (2 levels each) are applied in cvt_fold22 (f32, fused).
// R9 change: cvt_fold22 re-mapped to 4 cols/lane so every global load is a
// full-density float4 (16B stride 16B) and every store a full-density uint2
// (8B stride 8B) -- R8 had 50% density and 1.84x write amplification
// (WRITE_SIZE 117.8MB vs 64MB ideal, 80us @ 2.6TB/s).
// GEMM inner loop = R4/R7 proven structure (byte-identical).

typedef _Float16 half8 __attribute__((ext_vector_type(8)));
typedef float f32x4 __attribute__((ext_vector_type(4)));
typedef unsigned int uint32;

constexpr int TILE_E = 256 * 32;  // 8192 f16 = 16KB

__device__ __forceinline__ unsigned short f2h_bits(float f) {
  _Float16 h = (_Float16)f;
  return __builtin_bit_cast(unsigned short, h);
}

__device__ __forceinline__ void gload_lds16(const unsigned short* g, unsigned short* l) {
  __builtin_amdgcn_global_load_lds((const __attribute__((address_space(1))) void*)g,
                                   (__attribute__((address_space(3))) void*)l,
                                   16, 0, 0);
}

#define CFENCE asm volatile("" ::: "memory")

// Stored f16 index for logical (tile row r, 16B k-slot byte cb); stored rows
// are 128B (two logical rows); slot' = ((r&1)<<2 | cb>>4) ^ ((r>>1)&7).
// Measured 0 bank conflicts (R2-R8).
__device__ __forceinline__ int swz_idx(int r, int cbyte) {
  int b = (r >> 1) * 128 + ((((r & 1) << 6) | cbyte) ^ (((r >> 1) & 7) << 4));
  return b >> 1;
}

// Stage a 256x32 f16 tile from G (row-major, stride ld); LDS dest LINEAR,
// swizzle realized by inverse-permuting per-lane global source addresses.
__device__ __forceinline__ void stage_tile(const unsigned short* __restrict__ G,
                                           int rowbase, int k0, int ld,
                                           unsigned short* lds, int wave, int lane) {
#pragma unroll
  for (int c = 0; c < 2; ++c) {
    const int p = c * 64 + wave * 8 + (lane >> 3);   // stored 128B row
    const int v = (lane & 7) ^ ((lane >> 3) & 7);    // inverse slot swizzle
    const int r = 2 * p + (v >> 2);                  // logical tile row
    const int kslot = v & 3;
    const unsigned short* src = G + (size_t)(rowbase + r) * ld + (k0 + kslot * 8);
    unsigned short* dst = lds + (c * 64 + wave * 8) * 64;  // wave-uniform
    gload_lds16(src, dst);
  }
}

// ---- convert + FULL 2-level 2D fold (f32 in, f16 out), full-density I/O -----
// Thread (b, v<512, jc<128): 4 consecutive cols j0=jc*4. Reads x-rows
// {v, 2047-v, 1023-v, 1024+v} at col blocks {j0, 1020-j0, 1024+j0, 2044-j0}
// (each a float4, lane-contiguous). Emits 4 output rows x 4 streams, each a
// uint2 (4 f16), lane-contiguous (forward or descending).
__global__ __launch_bounds__(256) void cvt_fold22(const float* __restrict__ x,
                                                  unsigned short* __restrict__ Xff) {
  int tid = blockIdx.x * 256 + threadIdx.x;   // 524288 threads
  int m = tid >> 7;                           // b*512 + v
  int b = m >> 9;
  int v = m & 511;
  int j0 = (tid & 127) << 2;                  // [0,512) step 4
  const float* base = x + (size_t)b * 4194304;
  const float* rows[4] = {base + (size_t)v * 2048, base + (size_t)(2047 - v) * 2048,
                          base + (size_t)(1023 - v) * 2048, base + (size_t)(1024 + v) * 2048};
  unsigned short* o[4] = {
      Xff + ((size_t)b * 2048 + v) * 2048,          // Sp
      Xff + ((size_t)b * 2048 + 512 + v) * 2048,    // Sm
      Xff + ((size_t)b * 2048 + 1024 + v) * 2048,   // D_v
      Xff + ((size_t)b * 2048 + 2047 - v) * 2048};  // D_{1023-v}

  float4 va[4], vb[4], vc[4], vd[4];
#pragma unroll
  for (int t = 0; t < 4; ++t) {
    va[t] = *(const float4*)(rows[t] + j0);          // x[row][j0+e]
    vb[t] = *(const float4*)(rows[t] + 1020 - j0);   // x[row][1023-(j0+e)] rev
    vc[t] = *(const float4*)(rows[t] + 1024 + j0);   // x[row][1024+j0+e]
    vd[t] = *(const float4*)(rows[t] + 2044 - j0);   // x[row][2047-(j0+e)] rev
  }
  unsigned short up[4][4], um[4][4], wn[4][4], wm[4][4];
#pragma unroll
  for (int e4 = 0; e4 < 4; ++e4) {
    float A[4], Bq[4], C[4], Dq[4];
#pragma unroll
    for (int t = 0; t < 4; ++t) {
      A[t] = ((const float*)&va[t])[e4];
      Bq[t] = ((const float*)&vb[t])[3 - e4];
      C[t] = ((const float*)&vc[t])[e4];
      Dq[t] = ((const float*)&vd[t])[3 - e4];
    }
    // row combos: 0=Sp=(r0+r1)+(r2+r3); 1=Sm=(r0+r1)-(r2+r3); 2=r0-r1; 3=r2-r3
    float Av[4] = {A[0] + A[1] + A[2] + A[3], A[0] + A[1] - A[2] - A[3],
                   A[0] - A[1], A[2] - A[3]};
    float Bv[4] = {Bq[0] + Bq[1] + Bq[2] + Bq[3], Bq[0] + Bq[1] - Bq[2] - Bq[3],
                   Bq[0] - Bq[1], Bq[2] - Bq[3]};
    float Cv[4] = {C[0] + C[1] + C[2] + C[3], C[0] + C[1] - C[2] - C[3],
                   C[0] - C[1], C[2] - C[3]};
    float Dv[4] = {Dq[0] + Dq[1] + Dq[2] + Dq[3], Dq[0] + Dq[1] - Dq[2] - Dq[3],
                   Dq[0] - Dq[1], Dq[2] - Dq[3]};
#pragma unroll
    for (int t = 0; t < 4; ++t) {
      float un = Av[t] + Dv[t];   // u[n]
      float umr = Bv[t] + Cv[t];  // u[1023-n]
      up[t][e4] = f2h_bits(un + umr);
      um[t][e4] = f2h_bits(un - umr);
      wn[t][e4] = f2h_bits(Av[t] - Dv[t]);   // w[n]
      wm[t][e4] = f2h_bits(Bv[t] - Cv[t]);   // w[1023-n]
    }
  }
#pragma unroll
  for (int t = 0; t < 4; ++t) {
    *(uint2*)(o[t] + j0) =
        make_uint2(up[t][0] | ((uint32)up[t][1] << 16), up[t][2] | ((uint32)up[t][3] << 16));
    *(uint2*)(o[t] + 512 + j0) =
        make_uint2(um[t][0] | ((uint32)um[t][1] << 16), um[t][2] | ((uint32)um[t][3] << 16));
    *(uint2*)(o[t] + 1024 + j0) =
        make_uint2(wn[t][0] | ((uint32)wn[t][1] << 16), wn[t][2] | ((uint32)wn[t][3] << 16));
    // w_m: cols 2044-j0..2047-j0 hold wm[3],wm[2],wm[1],wm[0]
    *(uint2*)(o[t] + 2044 - j0) =
        make_uint2(wm[t][3] | ((uint32)wm[t][2] << 16), wm[t][1] | ((uint32)wm[t][0] << 16));
  }
}

// ---- cosine matrices: C4k 1024x1024 (DCT-IV), C2h 512x512, C4h 512x512 ------
__global__ __launch_bounds__(256) void gen_cos3(unsigned short* __restrict__ C4k,
                                                unsigned short* __restrict__ C2h,
                                                unsigned short* __restrict__ C4h) {
  int idx = blockIdx.x * 256 + threadIdx.x;  // 1572864
  const float s = 7.6699039394282061e-4f;    // pi/4096
  if (idx < 1048576) {
    int k = idx >> 10, n = idx & 1023;
    int t = ((2 * n + 1) * (2 * k + 1)) & 8191;   // cos(pi(2n+1)(2k+1)/4096)
    C4k[idx] = f2h_bits(cosf((float)t * s));
  } else if (idx < 1310720) {
    int i2 = idx - 1048576;
    int k = i2 >> 9, n = i2 & 511;
    int t = ((2 * n + 1) * 4 * k) & 8191;         // cos(pi(2n+1)k/1024)
    C2h[i2] = f2h_bits(cosf((float)t * s));
  } else {
    int i2 = idx - 1310720;
    int k = i2 >> 9, n = i2 & 511;
    int t = ((2 * n + 1) * (4 * k + 2)) & 8191;   // cos(pi(2n+1)(2k+1)/2048)
    C4h[i2] = f2h_bits(cosf((float)t * s));
  }
}

// ---- pipelined GEMM (R4/R7-proven inner loop) -------------------------------
// MODE 0 (stage 1, f16 transposed out U2t[b][ktrue][m2]):
//   SPLIT 0: A cols [1024,2048)=w, B=M0=C4k,  K=1024, ktrue=2c+1
//   SPLIT 1: cls=bn>>1: A cols cls*512 (u+/u-), B=C2h/C4h, K=512, ktrue=4c+2cls
// MODE 1 (stage 2, fp32 out):
//   SPLIT 0: A=C4k (M=1024), B=U2t[z] cols [1024,2048), K=1024, rtrue=2p+1
//   SPLIT 1: cls=by>>1: A=C2h/C4h, B=U2t[z] cols cls*512, K=512, rtrue=4p+2cls
template <int MODE, int SPLIT>
__global__ __launch_bounds__(512) void dct_gemm(
    const unsigned short* __restrict__ M0, const unsigned short* __restrict__ M1,
    const unsigned short* __restrict__ D, void* __restrict__ outp) {
  constexpr int K = SPLIT ? 512 : 1024;
  constexpr int NT = K / 32;
  __shared__ unsigned short As[4 * TILE_E];
  __shared__ unsigned short Bs[4 * TILE_E];

  const int tid = threadIdx.x;
  const int lane = tid & 63;
  const int wave = tid >> 6;
  const int wr = wave >> 2;
  const int wc = wave & 3;
  const int bmx = blockIdx.y;
  const int bnx = blockIdx.x;
  const int z = blockIdx.z;

  const unsigned short* Ag;
  const unsigned short* Bg;
  int lda, ldb, arow, brow, cls;
  if (MODE == 0) {
    cls = SPLIT ? (bnx >> 1) : 0;
    Ag = D + (SPLIT ? cls * 512 : 1024);
    lda = 2048;
    arow = bmx * 256;
    Bg = SPLIT ? (cls ? M1 : M0) : M0;
    ldb = K;
    brow = (SPLIT ? (bnx & 1) : bnx) * 256;
  } else {
    cls = SPLIT ? (bmx >> 1) : 0;
    Ag = SPLIT ? (cls ? M1 : M0) : M0;
    lda = K;
    arow = (SPLIT ? (bmx & 1) : bmx) * 256;
    Bg = D + (size_t)z * 4194304u + (SPLIT ? cls * 512 : 1024);
    ldb = 2048;
    brow = bnx * 256;
  }

  const int frc = lane & 15;
  const int cb = (lane >> 4) << 4;

  f32x4 acc[8][4] = {};

  stage_tile(Ag, arow, 0, lda, &As[0], wave, lane);
  stage_tile(Bg, brow, 0, ldb, &Bs[0], wave, lane);
  stage_tile(Ag, arow, 32, lda, &As[TILE_E], wave, lane);
  stage_tile(Bg, brow, 32, ldb, &Bs[TILE_E], wave, lane);
  asm volatile("s_waitcnt vmcnt(4)" ::: "memory");
  CFENCE; __builtin_amdgcn_s_barrier(); CFENCE;

  for (int t = 0; t < NT; ++t) {
    const unsigned short* at = &As[(t & 3) * TILE_E];
    const unsigned short* bt = &Bs[(t & 3) * TILE_E];
    half8 af[4], bf[4];

    // phase 1: reads (quadrant mh=0) + stage A(t+2)
#pragma unroll
    for (int m = 0; m < 4; ++m)
      af[m] = *(const half8*)&at[swz_idx(wr * 128 + m * 16 + frc, cb)];
#pragma unroll
    for (int n = 0; n < 4; ++n)
      bf[n] = *(const half8*)&bt[swz_idx(wc * 64 + n * 16 + frc, cb)];
    if (t + 2 < NT)
      stage_tile(Ag, arow, (t + 2) * 32, lda, &As[((t + 2) & 3) * TILE_E], wave, lane);
    CFENCE; __builtin_amdgcn_s_barrier(); CFENCE;
    __builtin_amdgcn_s_setprio(1);
#pragma unroll
    for (int m = 0; m < 4; ++m)
#pragma unroll
      for (int n = 0; n < 4; ++n)
        acc[m][n] = __builtin_amdgcn_mfma_f32_16x16x32_f16(af[m], bf[n], acc[m][n], 0, 0, 0);
    __builtin_amdgcn_s_setprio(0);

    // phase 2: reads (quadrant mh=1) + stage B(t+2) + counted boundary
#pragma unroll
    for (int m = 0; m < 4; ++m)
      af[m] = *(const half8*)&at[swz_idx(wr * 128 + 64 + m * 16 + frc, cb)];
    if (t + 2 < NT)
      stage_tile(Bg, brow, (t + 2) * 32, ldb, &Bs[((t + 2) & 3) * TILE_E], wave, lane);
    if (t < NT - 2)
      asm volatile("s_waitcnt vmcnt(4)" ::: "memory");
    else if (t == NT - 2)
      asm volatile("s_waitcnt vmcnt(0)" ::: "memory");
    CFENCE; __builtin_amdgcn_s_barrier(); CFENCE;
    __builtin_amdgcn_s_setprio(1);
#pragma unroll
    for (int m = 0; m < 4; ++m)
#pragma unroll
      for (int n = 0; n < 4; ++n)
        acc[m + 4][n] =
            __builtin_amdgcn_mfma_f32_16x16x32_f16(af[m], bf[n], acc[m + 4][n], 0, 0, 0);
    __builtin_amdgcn_s_setprio(0);
  }

  // epilogue; D mapping: col = lane&15, row = (lane>>4)*4 + i
  if (MODE == 0) {
    unsigned short* U2t = (unsigned short*)outp;
#pragma unroll
    for (int mi = 0; mi < 8; ++mi) {
      const int r = arow + wr * 128 + (mi >> 2) * 64 + (mi & 3) * 16 + (lane >> 4) * 4;
      const int b = r >> 11;
      const int rb = r & 2047;
#pragma unroll
      for (int n = 0; n < 4; ++n) {
        const int ccls = brow + wc * 64 + n * 16 + frc;
        const int ktrue = SPLIT ? (4 * ccls + 2 * cls) : (2 * ccls + 1);
        uint32 lo = f2h_bits(acc[mi][n][0]) | ((uint32)f2h_bits(acc[mi][n][1]) << 16);
        uint32 hi = f2h_bits(acc[mi][n][2]) | ((uint32)f2h_bits(acc[mi][n][3]) << 16);
        *(uint2*)&U2t[(size_t)b * 4194304 + (size_t)ktrue * 2048 + rb] =
            make_uint2(lo, hi);
      }
    }
  } else {
    float* out = (float*)outp + (size_t)z * 4194304;
#pragma unroll
    for (int mi = 0; mi < 8; ++mi) {
      const int p0 = arow + wr * 128 + (mi >> 2) * 64 + (mi & 3) * 16 + (lane >> 4) * 4;
#pragma unroll
      for (int n = 0; n < 4; ++n) {
        const int cg = brow + wc * 64 + n * 16 + frc;
#pragma unroll
        for (int i = 0; i < 4; ++i) {
          const int rtrue = SPLIT ? (4 * (p0 + i) + 2 * cls) : (2 * (p0 + i) + 1);
          out[(size_t)rtrue * 2048 + cg] = acc[mi][n][i];
        }
      }
    }
  }
}

extern "C" void kernel_launch(void* const* d_in, const int* in_sizes, int n_in,
                              void* d_out, int out_size, void* d_ws,
                              size_t ws_size, hipStream_t stream) {
  const float* x = (const float*)d_in[0];
  float* out = (float*)d_out;

  // workspace (f16 elems):
  // Xff 33554432 | C4k 1048576 | C2h 262144 | C4h 262144 | U2t 33554432
  unsigned short* Xff = (unsigned short*)d_ws;
  unsigned short* C4k = Xff + 33554432u;
  unsigned short* C2h = C4k + 1048576u;
  unsigned short* C4h = C2h + 262144u;
  unsigned short* U2t = C4h + 262144u;

  cvt_fold22<<<2048, 256, 0, stream>>>(x, Xff);
  gen_cos3<<<6144, 256, 0, stream>>>(C4k, C2h, C4h);
  // stage 1: odd k (K=1024) and even k (K=512, u+/u- classes)
  dct_gemm<0, 0><<<dim3(4, 64, 1), 512, 0, stream>>>(C4k, C4k, Xff, (void*)U2t);
  dct_gemm<0, 1><<<dim3(4, 64, 1), 512, 0, stream>>>(C2h, C4h, Xff, (void*)U2t);
  // stage 2: odd rows (K=1024) and even rows (K=512)
  dct_gemm<1, 0><<<dim3(8, 4, 8), 512, 0, stream>>>(C4k, C4k, U2t, (void*)out);
  dct_gemm<1, 1><<<dim3(8, 4, 8), 512, 0, stream>>>(C2h, C4h, U2t, (void*)out);
}